// Round 2
// baseline (208.910 us; speedup 1.0000x reference)
//
#include <hip/hip_runtime.h>
#include <hip/hip_bf16.h>

#define B_ 4
#define T_ 4096
#define C_ 1024
#define H_ 64

typedef float  f32x4  __attribute__((ext_vector_type(4)));
typedef short  bf16x8 __attribute__((ext_vector_type(8)));
typedef ushort u16x8  __attribute__((ext_vector_type(8)));

static __device__ __forceinline__ ushort f2bf(float f) {
  union { float f; uint u; } v; v.f = f;
  uint u = v.u;
  u += 0x7FFFu + ((u >> 16) & 1u);   // round-to-nearest-even
  return (ushort)(u >> 16);
}

#define MFMA(a, b, c) __builtin_amdgcn_mfma_f32_16x16x32_bf16(a, b, c, 0, 0, 0)

// ---------------------------------------------------------------------------
// Wt[w][n][c] = W_w[c][n] as bf16  (w in {q,k,v})
__global__ __launch_bounds__(256) void wt_prep(const float* __restrict__ Wq,
                                               const float* __restrict__ Wk,
                                               const float* __restrict__ Wv,
                                               ushort* __restrict__ Wt) {
  int idx = blockIdx.x * 256 + threadIdx.x;   // 3*64*1024 = 196608
  int w = idx >> 16, rem = idx & 65535;
  int n = rem >> 10, c = rem & 1023;
  const float* W = (w == 0) ? Wq : (w == 1) ? Wk : Wv;
  Wt[idx] = f2bf(W[c * 64 + n]);
}

// ---------------------------------------------------------------------------
// QKV projection, no LDS, no barriers. 1 wave = 16 rows. W B-frags from L1.
// Q,K: [b][t][h] bf16.  V: transposed [b][h][t] bf16.
__global__ __launch_bounds__(256) void qkv_proj(const float* __restrict__ x,
                                                const ushort* __restrict__ Wt,
                                                ushort* __restrict__ Qg,
                                                ushort* __restrict__ Kg,
                                                ushort* __restrict__ Vt) {
  const int tid = threadIdx.x;
  const int lane = tid & 63, wid = tid >> 6;
  const int b = blockIdx.x >> 6, rt = blockIdx.x & 63;
  const int l15 = lane & 15, g = lane >> 4;
  const int row = rt * 64 + wid * 16 + l15;

  f32x4 acc[3][4];
  #pragma unroll
  for (int w = 0; w < 3; w++)
    #pragma unroll
    for (int nt = 0; nt < 4; nt++) acc[w][nt] = (f32x4)0.0f;

  const float* xr = x + ((size_t)b * T_ + row) * C_ + g * 8;

  // software pipeline: prefetch next 64-k chunk of x while computing current
  f32x4 nx0 = *(const f32x4*)xr;
  f32x4 nx1 = *(const f32x4*)(xr + 4);
  f32x4 nx2 = *(const f32x4*)(xr + 32);
  f32x4 nx3 = *(const f32x4*)(xr + 36);

  for (int k0 = 0; k0 < C_; k0 += 64) {
    f32x4 c0 = nx0, c1 = nx1, c2 = nx2, c3 = nx3;
    if (k0 + 64 < C_) {
      const float* nxt = xr + k0 + 64;
      nx0 = *(const f32x4*)nxt;
      nx1 = *(const f32x4*)(nxt + 4);
      nx2 = *(const f32x4*)(nxt + 32);
      nx3 = *(const f32x4*)(nxt + 36);
    }
    union { u16x8 u; bf16x8 s; } ua, ub;
    #pragma unroll
    for (int j = 0; j < 4; j++) {
      ua.u[j] = f2bf(c0[j]); ua.u[4 + j] = f2bf(c1[j]);
      ub.u[j] = f2bf(c2[j]); ub.u[4 + j] = f2bf(c3[j]);
    }
    bf16x8 a0 = ua.s, a1 = ub.s;

    #pragma unroll
    for (int w = 0; w < 3; w++) {
      #pragma unroll
      for (int nt = 0; nt < 4; nt++) {
        const ushort* wp = Wt + (size_t)(w * 64 + nt * 16 + l15) * C_ + k0 + g * 8;
        bf16x8 b0 = *(const bf16x8*)wp;
        bf16x8 b1 = *(const bf16x8*)(wp + 32);
        acc[w][nt] = MFMA(a0, b0, acc[w][nt]);
        acc[w][nt] = MFMA(a1, b1, acc[w][nt]);
      }
    }
  }

  // epilogue: C-frag is col=lane&15, row=(lane>>4)*4+reg  [m89-verified]
  const int qb = rt * 64 + wid * 16 + g * 4;
  #pragma unroll
  for (int nt = 0; nt < 4; nt++) {
    int n = nt * 16 + l15;
    #pragma unroll
    for (int r = 0; r < 4; r++) {
      size_t o = ((size_t)b * T_ + qb + r) * H_ + n;
      Qg[o] = f2bf(acc[0][nt][r]);
      Kg[o] = f2bf(acc[1][nt][r]);
    }
    ushort hv[4];
    #pragma unroll
    for (int r = 0; r < 4; r++) hv[r] = f2bf(acc[2][nt][r]);
    *(uint2*)(Vt + ((size_t)b * H_ + n) * T_ + qb) = *(const uint2*)hv;
  }
}

// ---------------------------------------------------------------------------
// Flash attention, no-max softmax, key-split partials, ZERO barriers.
// Block = 4 waves x 16 q-rows. K/V B-frags read directly from global (L1/L2).
// If Op==nullptr: direct mode (full key range, normalize + write out).
__global__ __launch_bounds__(256) void attn(const ushort* __restrict__ Qg,
                                            const ushort* __restrict__ Kg,
                                            const ushort* __restrict__ Vt,
                                            float* __restrict__ Op,
                                            float* __restrict__ Ds,
                                            float* __restrict__ out,
                                            int KT) {
  __shared__ ushort psm[4][16 * 64];    // per-wave P [q][key], swizzled
  const int tid = threadIdx.x;
  const int lane = tid & 63, wid = tid >> 6;
  const int bid = blockIdx.x;
  const int s = bid >> 8, r8 = bid & 255;
  const int b = r8 >> 6, qt = r8 & 63;
  const int l15 = lane & 15, g = lane >> 4;
  const int sw = (l15 & 7) << 4;
  char* pb = (char*)psm + wid * 2048;

  // Q A-frags: row = lane&15 (q), k = dim
  const ushort* qp = Qg + ((size_t)b * T_ + qt * 64 + wid * 16 + l15) * H_ + g * 8;
  bf16x8 qa0 = *(const bf16x8*)qp;
  bf16x8 qa1 = *(const bf16x8*)(qp + 32);

  f32x4 acco[4];
  #pragma unroll
  for (int nt = 0; nt < 4; nt++) acco[nt] = (f32x4)0.0f;
  float dsum[4] = {0.f, 0.f, 0.f, 0.f};

  const ushort* kbase = Kg + (size_t)b * T_ * H_;
  const ushort* vbase = Vt + (size_t)b * H_ * T_;
  const int kt0 = s * KT;

  for (int kt = kt0; kt < kt0 + KT; kt++) {
    // S = Q K^T   (B-frag: col=key, k=dim, direct from K[key][dim] rows)
    f32x4 sacc[4];
    #pragma unroll
    for (int nt = 0; nt < 4; nt++) sacc[nt] = (f32x4)0.0f;
    const ushort* kp = kbase + (size_t)(kt * 64 + l15) * H_ + g * 8;
    #pragma unroll
    for (int nt = 0; nt < 4; nt++) {
      const ushort* kr = kp + nt * 16 * H_;
      bf16x8 kb0 = *(const bf16x8*)kr;
      bf16x8 kb1 = *(const bf16x8*)(kr + 32);
      sacc[nt] = MFMA(qa0, kb0, sacc[nt]);
      sacc[nt] = MFMA(qa1, kb1, sacc[nt]);
    }

    // P = exp(S*scale), accumulate denominator, spill P (bf16) to wave LDS
    #pragma unroll
    for (int nt = 0; nt < 4; nt++) {
      int key2 = (nt * 16 + l15) * 2;
      #pragma unroll
      for (int r = 0; r < 4; r++) {
        float p = __builtin_amdgcn_exp2f(sacc[nt][r] * 0.18033688011112042f);
        dsum[r] += p;
        int qq = g * 4 + r;
        *(ushort*)(pb + ((qq * 128 + key2) ^ ((qq & 7) << 4))) = f2bf(p);
      }
    }

    // P A-frags: row = lane&15 (q), k = key (wave-local LDS, no barrier)
    bf16x8 pa0 = *(const bf16x8*)(pb + ((l15 * 128 + g * 16) ^ sw));
    bf16x8 pa1 = *(const bf16x8*)(pb + ((l15 * 128 + 64 + g * 16) ^ sw));

    // O += P V   (B-frag: col=dim, k=key, direct from V^T[dim][key] rows)
    const ushort* vp = vbase + (size_t)l15 * T_ + kt * 64 + g * 8;
    #pragma unroll
    for (int nt = 0; nt < 4; nt++) {
      const ushort* vr = vp + (size_t)(nt * 16) * T_;
      bf16x8 vb0 = *(const bf16x8*)vr;
      bf16x8 vb1 = *(const bf16x8*)(vr + 32);
      acco[nt] = MFMA(pa0, vb0, acco[nt]);
      acco[nt] = MFMA(pa1, vb1, acco[nt]);
    }
  }

  // reduce denominator across the 16 lanes of each group (keys axis)
  #pragma unroll
  for (int r = 0; r < 4; r++) {
    float d = dsum[r];
    #pragma unroll
    for (int m = 1; m < 16; m <<= 1) d += __shfl_xor(d, m, 64);
    dsum[r] = d;
  }

  const int row0 = qt * 64 + wid * 16 + g * 4;
  if (Op != nullptr) {
    float* ob = Op + ((size_t)(s * 4 + b) * T_ + row0) * H_;
    #pragma unroll
    for (int nt = 0; nt < 4; nt++) {
      int dim = nt * 16 + l15;
      #pragma unroll
      for (int r = 0; r < 4; r++) ob[r * H_ + dim] = acco[nt][r];
    }
    if (l15 == 0) {
      #pragma unroll
      for (int r = 0; r < 4; r++) Ds[(size_t)(s * 4 + b) * T_ + row0 + r] = dsum[r];
    }
  } else {
    float inv[4];
    #pragma unroll
    for (int r = 0; r < 4; r++) inv[r] = 1.0f / dsum[r];
    float* ob = out + ((size_t)b * T_ + row0) * H_;
    #pragma unroll
    for (int nt = 0; nt < 4; nt++) {
      int dim = nt * 16 + l15;
      #pragma unroll
      for (int r = 0; r < 4; r++) ob[r * H_ + dim] = acco[nt][r] * inv[r];
    }
  }
}

// ---------------------------------------------------------------------------
// out[row][h] = sum_s Op[s][row][h] / sum_s Ds[s][row]
__global__ __launch_bounds__(256) void reduce_seg(const float* __restrict__ Op,
                                                  const float* __restrict__ Ds,
                                                  float* __restrict__ out, int seg) {
  int i = blockIdx.x * 256 + threadIdx.x;       // over 4*4096*16 f32x4 groups
  size_t e = (size_t)i * 4;
  int row = (int)(e >> 6);
  f32x4 o = (f32x4)0.0f;
  float d = 0.0f;
  for (int s = 0; s < seg; s++) {
    o += *(const f32x4*)(Op + (size_t)s * (4u * T_ * H_) + e);
    d += Ds[(size_t)s * (4u * T_) + row];
  }
  *(f32x4*)(out + e) = o * (1.0f / d);
}

// ---------------------------------------------------------------------------
extern "C" void kernel_launch(void* const* d_in, const int* in_sizes, int n_in,
                              void* d_out, int out_size, void* d_ws, size_t ws_size,
                              hipStream_t stream) {
  const float* x  = (const float*)d_in[0];
  const float* Wq = (const float*)d_in[1];
  const float* Wk = (const float*)d_in[2];
  const float* Wv = (const float*)d_in[3];
  float* out = (float*)d_out;

  char* ws = (char*)d_ws;
  size_t off = 0;
  auto take = [&](size_t n) -> void* {
    void* p = ws + off;
    off = (off + n + 255) & ~(size_t)255;
    return p;
  };
  ushort* Qg = (ushort*)take((size_t)B_ * T_ * H_ * 2);   // 2 MB
  ushort* Kg = (ushort*)take((size_t)B_ * T_ * H_ * 2);   // 2 MB
  ushort* Vt = (ushort*)take((size_t)B_ * T_ * H_ * 2);   // 2 MB
  ushort* Wt = (ushort*)take((size_t)3 * H_ * C_ * 2);    // 384 KB
  size_t base = off;

  // pick largest key-split that fits the workspace
  int seg = 0;
  for (int s = 8; s >= 2; s >>= 1) {
    size_t need = base + (size_t)s * B_ * T_ * H_ * 4 + 256 + (size_t)s * B_ * T_ * 4 + 256;
    if (need <= ws_size) { seg = s; break; }
  }
  float* Op = nullptr;
  float* Ds = nullptr;
  int KT = 64;
  if (seg) {
    Op = (float*)take((size_t)seg * B_ * T_ * H_ * 4);
    Ds = (float*)take((size_t)seg * B_ * T_ * 4);
    KT = 64 / seg;
  } else {
    seg = 1;
  }

  wt_prep<<<768, 256, 0, stream>>>(Wq, Wk, Wv, Wt);
  qkv_proj<<<B_ * (T_ / 64), 256, 0, stream>>>(x, Wt, Qg, Kg, Vt);
  attn<<<B_ * (T_ / 64) * seg, 256, 0, stream>>>(Qg, Kg, Vt, Op, Ds, out, KT);
  if (Op) reduce_seg<<<(B_ * T_ * H_ / 4 + 255) / 256, 256, 0, stream>>>(Op, Ds, out, seg);
}

// Round 3
// 80.457 us; speedup vs baseline: 2.5965x; 2.5965x over previous
//
#include <hip/hip_runtime.h>
#include <hip/hip_bf16.h>

#define B_ 4
#define T_ 4096
#define C_ 1024
#define H_ 64

typedef float  f32x4  __attribute__((ext_vector_type(4)));
typedef short  bf16x8 __attribute__((ext_vector_type(8)));
typedef ushort u16x8  __attribute__((ext_vector_type(8)));
typedef uint   u32x4  __attribute__((ext_vector_type(4)));

static __device__ __forceinline__ ushort f2bf(float f) {
  union { float f; uint u; } v; v.f = f;
  uint u = v.u;
  u += 0x7FFFu + ((u >> 16) & 1u);   // round-to-nearest-even
  return (ushort)(u >> 16);
}

static __device__ __forceinline__ void gload_lds16(const void* g, void* l) {
  __builtin_amdgcn_global_load_lds(
      (const __attribute__((address_space(1))) unsigned int*)g,
      (__attribute__((address_space(3))) unsigned int*)l, 16, 0, 0);
}

#define MFMA(a, b, c) __builtin_amdgcn_mfma_f32_16x16x32_bf16(a, b, c, 0, 0, 0)

// ---------------------------------------------------------------------------
// Wt[w][n][c] = W_w[c][n] as bf16  (w in {q,k,v})
__global__ __launch_bounds__(256) void wt_prep(const float* __restrict__ Wq,
                                               const float* __restrict__ Wk,
                                               const float* __restrict__ Wv,
                                               ushort* __restrict__ Wt) {
  int idx = blockIdx.x * 256 + threadIdx.x;   // 3*64*1024 = 196608
  int w = idx >> 16, rem = idx & 65535;
  int n = rem >> 10, c = rem & 1023;
  const float* W = (w == 0) ? Wq : (w == 1) ? Wk : Wv;
  Wt[idx] = f2bf(W[c * 64 + n]);
}

// ---------------------------------------------------------------------------
// QKV projection (LDS-staged, round-1 structure).
// Outputs:
//   Qg: [b][t][h] bf16 linear.
//   Kb: per-(b, t/64) 8KB tile: byte (key*128 + h*2) ^ ((key&7)<<4),  key=t&63
//   Vb: per-(b, t/128) 16KB tile: byte (h*256 + key*2) ^ ((h&7)<<4),  key=t&127
__global__ __launch_bounds__(256) void qkv_proj(const float* __restrict__ x,
                                                const ushort* __restrict__ Wt,
                                                ushort* __restrict__ Qg,
                                                char* __restrict__ Kb,
                                                char* __restrict__ Vb) {
  __shared__ ushort xs[64 * 64];        // [row][k] bf16, XOR-swizzled
  __shared__ ushort wl[3 * 64 * 64];    // [w][n][k] bf16, XOR-swizzled
  const int tid = threadIdx.x;
  const int lane = tid & 63, wid = tid >> 6;
  const int b = blockIdx.x >> 6, rt = blockIdx.x & 63;
  const int l15 = lane & 15, g = lane >> 4;
  const int sw = (l15 & 7) << 4;
  char* xsb = (char*)xs;
  char* wlb = (char*)wl;

  f32x4 acc[3][4];
  #pragma unroll
  for (int w = 0; w < 3; w++)
    #pragma unroll
    for (int nt = 0; nt < 4; nt++) acc[w][nt] = (f32x4)0.0f;

  const float* xb = x + ((size_t)b * T_ + rt * 64) * C_;

  const int arow = wid * 16 + l15;
  const int aoff0 = ((arow * 128 + g * 16) ^ ((arow & 7) << 4));
  const int aoff1 = ((arow * 128 + 64 + g * 16) ^ ((arow & 7) << 4));

  for (int k0 = 0; k0 < C_; k0 += 64) {
    // stage x tile [64 rows][64 k] -> bf16, swizzled
    #pragma unroll
    for (int i = 0; i < 2; i++) {
      int c = tid + i * 256;
      int row = c >> 3, ko = (c & 7) * 8;
      const float* src = xb + (size_t)row * C_ + k0 + ko;
      f32x4 a0 = *(const f32x4*)src;
      f32x4 a1 = *(const f32x4*)(src + 4);
      u16x8 h;
      #pragma unroll
      for (int j = 0; j < 4; j++) { h[j] = f2bf(a0[j]); h[4 + j] = f2bf(a1[j]); }
      *(u16x8*)(xsb + ((row * 128 + ko * 2) ^ ((row & 7) << 4))) = h;
    }
    // stage Wt tiles [3][n=64][k=64]
    #pragma unroll
    for (int i = 0; i < 6; i++) {
      int cc = tid + i * 256;
      int w = cc >> 9, rem = cc & 511, n = rem >> 3, o16 = rem & 7;
      u32x4 v = *(const u32x4*)(Wt + (size_t)(w * 64 + n) * C_ + k0 + o16 * 8);
      *(u32x4*)(wlb + ((w * 8192 + n * 128 + o16 * 16) ^ ((n & 7) << 4))) = v;
    }
    __syncthreads();

    bf16x8 xa0 = *(const bf16x8*)(xsb + aoff0);
    bf16x8 xa1 = *(const bf16x8*)(xsb + aoff1);
    #pragma unroll
    for (int w = 0; w < 3; w++) {
      #pragma unroll
      for (int nt = 0; nt < 4; nt++) {
        int n = nt * 16 + l15;
        bf16x8 b0 = *(const bf16x8*)(wlb + ((w * 8192 + n * 128 + g * 16) ^ sw));
        bf16x8 b1 = *(const bf16x8*)(wlb + ((w * 8192 + n * 128 + 64 + g * 16) ^ sw));
        acc[w][nt] = MFMA(xa0, b0, acc[w][nt]);
        acc[w][nt] = MFMA(xa1, b1, acc[w][nt]);
      }
    }
    __syncthreads();
  }

  // epilogue: C-frag is col=lane&15, row=(lane>>4)*4+reg  [m89-verified]
  const int qb = rt * 64 + wid * 16 + g * 4;
  char* kdst = Kb + (size_t)(b * 64 + rt) * 8192;
  char* vdst = Vb + (size_t)(b * 32 + (rt >> 1)) * 16384;
  const int key0 = (rt & 1) * 64 + wid * 16 + g * 4;
  #pragma unroll
  for (int nt = 0; nt < 4; nt++) {
    int n = nt * 16 + l15;
    #pragma unroll
    for (int r = 0; r < 4; r++) {
      Qg[((size_t)b * T_ + qb + r) * H_ + n] = f2bf(acc[0][nt][r]);
      int key = wid * 16 + g * 4 + r;
      *(ushort*)(kdst + ((key * 128 + n * 2) ^ ((key & 7) << 4))) = f2bf(acc[1][nt][r]);
    }
    ushort hv[4];
    #pragma unroll
    for (int r = 0; r < 4; r++) hv[r] = f2bf(acc[2][nt][r]);
    *(uint2*)(vdst + ((n * 256 + key0 * 2) ^ ((n & 7) << 4))) = *(const uint2*)hv;
  }
}

// ---------------------------------------------------------------------------
// Flash attention, no-max softmax, key-split partials.
// Block = 4 waves x 16 q-rows = 64 q-rows. KVBLK = 128 keys/iter.
// K/V staged to LDS via global_load_lds (pre-swizzled global layout),
// double-buffered, ONE barrier per iteration.
__global__ __launch_bounds__(256) void attn(const ushort* __restrict__ Qg,
                                            const char* __restrict__ Kb,
                                            const char* __restrict__ Vb,
                                            float* __restrict__ Op,
                                            float* __restrict__ Ds,
                                            float* __restrict__ out,
                                            int KT) {
  __shared__ char kv[2][32768];         // [buf][K 16KB | V 16KB], swizzled
  __shared__ char psm[4][4096];         // per-wave P [q16][key128] bf16, swizzled
  const int tid = threadIdx.x;
  const int lane = tid & 63, wid = tid >> 6;
  const int bid = blockIdx.x;
  const int s = bid >> 8, r8 = bid & 255;
  const int b = r8 >> 6, qt = r8 & 63;
  const int l15 = lane & 15, g = lane >> 4;
  char* pb = psm[wid];

  // Q A-frags: row = lane&15 (q), k = dim
  const ushort* qp = Qg + ((size_t)b * T_ + qt * 64 + wid * 16 + l15) * H_ + g * 8;
  bf16x8 qa0 = *(const bf16x8*)qp;
  bf16x8 qa1 = *(const bf16x8*)(qp + 32);

  f32x4 acco[4];
  #pragma unroll
  for (int nt = 0; nt < 4; nt++) acco[nt] = (f32x4)0.0f;
  float dsum[4] = {0.f, 0.f, 0.f, 0.f};

  const char* kbase = Kb + (size_t)b * 64 * 8192;   // 64 tiles of 8KB per b
  const char* vbase = Vb + (size_t)b * 32 * 16384;  // 32 tiles of 16KB per b
  const int kt0 = s * KT;

  // stage(buf, kt): copy K(16KB)+V(16KB) for 128-key tile kt, linear.
  auto stage = [&](int buf, int kt) {
    char* dst = kv[buf] + tid * 16;
    const char* ks = kbase + (size_t)kt * 16384 + tid * 16;
    const char* vs = vbase + (size_t)kt * 16384 + tid * 16;
    #pragma unroll
    for (int p = 0; p < 4; p++) gload_lds16(ks + p * 4096, dst + p * 4096);
    #pragma unroll
    for (int p = 0; p < 4; p++) gload_lds16(vs + p * 4096, dst + 16384 + p * 4096);
  };

  stage(0, kt0);
  __syncthreads();

  for (int it = 0; it < KT; it++) {
    const int cur = it & 1;
    if (it + 1 < KT) stage(cur ^ 1, kt0 + it + 1);
    const char* kt_lds = kv[cur];
    const char* vt_lds = kv[cur] + 16384;

    // S = Q K^T over 128 keys (8 x 16-key column tiles)
    f32x4 sacc[8];
    #pragma unroll
    for (int nt = 0; nt < 8; nt++) sacc[nt] = (f32x4)0.0f;
    #pragma unroll
    for (int nt = 0; nt < 8; nt++) {
      int k6 = (nt & 3) * 16 + l15;                  // key within 64-key subtile
      const char* kr = kt_lds + (nt >> 2) * 8192;
      bf16x8 kb0 = *(const bf16x8*)(kr + ((k6 * 128 + g * 16) ^ ((k6 & 7) << 4)));
      bf16x8 kb1 = *(const bf16x8*)(kr + ((k6 * 128 + 64 + g * 16) ^ ((k6 & 7) << 4)));
      sacc[nt] = MFMA(qa0, kb0, sacc[nt]);
      sacc[nt] = MFMA(qa1, kb1, sacc[nt]);
    }

    // P = exp(S*scale), accumulate denominator, spill P (bf16) to wave LDS
    #pragma unroll
    for (int nt = 0; nt < 8; nt++) {
      int key2 = (nt * 16 + l15) * 2;
      #pragma unroll
      for (int r = 0; r < 4; r++) {
        float p = __builtin_amdgcn_exp2f(sacc[nt][r] * 0.18033688011112042f);
        dsum[r] += p;
        int qq = g * 4 + r;
        *(ushort*)(pb + ((qq * 256 + key2) ^ ((qq & 7) << 4))) = f2bf(p);
      }
    }

    // O += P V  (A: P rows, k=32-key groups; B: V^T[dim][key])
    #pragma unroll
    for (int kk = 0; kk < 4; kk++) {
      bf16x8 pa = *(const bf16x8*)(pb + ((l15 * 256 + kk * 64 + g * 16) ^ ((l15 & 7) << 4)));
      #pragma unroll
      for (int nt = 0; nt < 4; nt++) {
        int d = nt * 16 + l15;
        bf16x8 vv = *(const bf16x8*)(vt_lds + ((d * 256 + kk * 64 + g * 16) ^ ((d & 7) << 4)));
        acco[nt] = MFMA(pa, vv, acco[nt]);
      }
    }
    __syncthreads();
  }

  // reduce denominator across the 16 lanes of each group (keys axis)
  #pragma unroll
  for (int r = 0; r < 4; r++) {
    float d = dsum[r];
    #pragma unroll
    for (int m = 1; m < 16; m <<= 1) d += __shfl_xor(d, m, 64);
    dsum[r] = d;
  }

  const int row0 = qt * 64 + wid * 16 + g * 4;
  if (Op != nullptr) {
    float* ob = Op + ((size_t)(s * 4 + b) * T_ + row0) * H_;
    #pragma unroll
    for (int nt = 0; nt < 4; nt++) {
      int dim = nt * 16 + l15;
      #pragma unroll
      for (int r = 0; r < 4; r++) ob[r * H_ + dim] = acco[nt][r];
    }
    if (l15 == 0) {
      #pragma unroll
      for (int r = 0; r < 4; r++) Ds[(size_t)(s * 4 + b) * T_ + row0 + r] = dsum[r];
    }
  } else {
    float inv[4];
    #pragma unroll
    for (int r = 0; r < 4; r++) inv[r] = 1.0f / dsum[r];
    float* ob = out + ((size_t)b * T_ + row0) * H_;
    #pragma unroll
    for (int nt = 0; nt < 4; nt++) {
      int dim = nt * 16 + l15;
      #pragma unroll
      for (int r = 0; r < 4; r++) ob[r * H_ + dim] = acco[nt][r] * inv[r];
    }
  }
}

// ---------------------------------------------------------------------------
// out[row][h] = sum_s Op[s][row][h] / sum_s Ds[s][row]
__global__ __launch_bounds__(256) void reduce_seg(const float* __restrict__ Op,
                                                  const float* __restrict__ Ds,
                                                  float* __restrict__ out, int seg) {
  int i = blockIdx.x * 256 + threadIdx.x;       // over 4*4096*16 f32x4 groups
  size_t e = (size_t)i * 4;
  int row = (int)(e >> 6);
  f32x4 o = (f32x4)0.0f;
  float d = 0.0f;
  for (int s = 0; s < seg; s++) {
    o += *(const f32x4*)(Op + (size_t)s * (4u * T_ * H_) + e);
    d += Ds[(size_t)s * (4u * T_) + row];
  }
  *(f32x4*)(out + e) = o * (1.0f / d);
}

// ---------------------------------------------------------------------------
extern "C" void kernel_launch(void* const* d_in, const int* in_sizes, int n_in,
                              void* d_out, int out_size, void* d_ws, size_t ws_size,
                              hipStream_t stream) {
  const float* x  = (const float*)d_in[0];
  const float* Wq = (const float*)d_in[1];
  const float* Wk = (const float*)d_in[2];
  const float* Wv = (const float*)d_in[3];
  float* out = (float*)d_out;

  char* ws = (char*)d_ws;
  size_t off = 0;
  auto take = [&](size_t n) -> void* {
    void* p = ws + off;
    off = (off + n + 255) & ~(size_t)255;
    return p;
  };
  ushort* Qg = (ushort*)take((size_t)B_ * T_ * H_ * 2);   // 2 MB
  char*   Kb = (char*)take((size_t)B_ * T_ * H_ * 2);     // 2 MB (blocked)
  char*   Vb = (char*)take((size_t)B_ * T_ * H_ * 2);     // 2 MB (blocked)
  ushort* Wt = (ushort*)take((size_t)3 * H_ * C_ * 2);    // 384 KB

  // key-split: 2 segments if workspace allows (partials: 8 MB + 64 KB)
  int seg = 1;
  float* Op = nullptr;
  float* Ds = nullptr;
  int KT = 32;                                            // 128-key tiles
  {
    size_t need = off + (size_t)2 * B_ * T_ * H_ * 4 + 256 + (size_t)2 * B_ * T_ * 4 + 256;
    if (need <= ws_size) {
      seg = 2;
      Op = (float*)take((size_t)seg * B_ * T_ * H_ * 4);
      Ds = (float*)take((size_t)seg * B_ * T_ * 4);
      KT = 16;
    }
  }

  wt_prep<<<768, 256, 0, stream>>>(Wq, Wk, Wv, Wt);
  qkv_proj<<<B_ * (T_ / 64), 256, 0, stream>>>(x, Wt, Qg, Kb, Vb);
  attn<<<B_ * (T_ / 64) * seg, 256, 0, stream>>>(Qg, Kb, Vb, Op, Ds, out, KT);
  if (Op) reduce_seg<<<(B_ * T_ * H_ / 4 + 255) / 256, 256, 0, stream>>>(Op, Ds, out, seg);
}

// Round 4
// 69.611 us; speedup vs baseline: 3.0011x; 1.1558x over previous
//
#include <hip/hip_runtime.h>
#include <hip/hip_bf16.h>

#define B_ 4
#define T_ 4096
#define C_ 1024
#define H_ 64

typedef float  f32x4  __attribute__((ext_vector_type(4)));
typedef short  bf16x8 __attribute__((ext_vector_type(8)));
typedef uint   u32x4  __attribute__((ext_vector_type(4)));

static __device__ __forceinline__ ushort f2bf(float f) {
  union { float f; uint u; } v; v.f = f;
  uint u = v.u;
  u += 0x7FFFu + ((u >> 16) & 1u);   // round-to-nearest-even
  return (ushort)(u >> 16);
}

// pack two f32 -> u32 of 2 bf16 (lo = s0, hi = s1), RTNE  [gfx950; no builtin]
static __device__ __forceinline__ uint cvtpk(float s0, float s1) {
  uint r;
  asm("v_cvt_pk_bf16_f32 %0, %1, %2" : "=v"(r) : "v"(s0), "v"(s1));
  return r;
}

static __device__ __forceinline__ void gload_lds16(const void* g, void* l) {
  __builtin_amdgcn_global_load_lds(
      (const __attribute__((address_space(1))) unsigned int*)g,
      (__attribute__((address_space(3))) unsigned int*)l, 16, 0, 0);
}

#define MFMA(a, b, c) __builtin_amdgcn_mfma_f32_16x16x32_bf16(a, b, c, 0, 0, 0)

// ---------------------------------------------------------------------------
// WtF: W in B-frag order: [w][c64 16][kc 2][nt 4][lane 64][j 8]
//   value = W_w[c = c64*64 + kc*32 + (lane>>4)*8 + j][n = nt*16 + (lane&15)]
__global__ __launch_bounds__(256) void wt_prep(const float* __restrict__ Wq,
                                               const float* __restrict__ Wk,
                                               const float* __restrict__ Wv,
                                               ushort* __restrict__ WtF) {
  int idx = blockIdx.x * 256 + threadIdx.x;   // 3*16*2*4*64*8 = 196608
  int j = idx & 7, lane = (idx >> 3) & 63, nt = (idx >> 9) & 3;
  int kc = (idx >> 11) & 1, c64 = (idx >> 12) & 15, w = idx >> 16;
  int l15 = lane & 15, g = lane >> 4;
  int c = c64 * 64 + kc * 32 + g * 8 + j;
  int n = nt * 16 + l15;
  const float* W = (w == 0) ? Wq : (w == 1) ? Wk : Wv;
  WtF[idx] = f2bf(W[c * 64 + n]);
}

// ---------------------------------------------------------------------------
// QKV projection: 1 wave per block (16 rows), barrier-free, W frags from L1.
// Outputs:
//   Qg:  [b][t][h] bf16 linear
//   Kb:  per-(b, t/64) 8KB tile: byte (key*128 + h*2) ^ ((key&7)<<4), key=t&63
//   VaF: per-(b, t/32) 4KB frag-block [ntd 4][lane 64][j 8]:
//        element = V[32G + phi(slot)][16ntd + l15],  slot = (lane>>4)*8 + j
//        phi^-1(k) : g' = ((k>>4)<<1)|((k>>2)&1), j = ((k>>3)&1)*4 + (k&3)
__global__ __launch_bounds__(64) void qkv_proj(const float* __restrict__ x,
                                               const ushort* __restrict__ WtF,
                                               ushort* __restrict__ Qg,
                                               char* __restrict__ Kb,
                                               char* __restrict__ VaF) {
  __shared__ __align__(16) ushort xs[2][16 * 64];   // 4KB, wave-private, swizzled
  const int lane = threadIdx.x;
  const int l15 = lane & 15, g = lane >> 4;
  const int b = blockIdx.x >> 8, rt = blockIdx.x & 255;
  const int row0 = rt * 16;

  f32x4 acc[3][4];
  #pragma unroll
  for (int w = 0; w < 3; w++)
    #pragma unroll
    for (int nt = 0; nt < 4; nt++) acc[w][nt] = (f32x4)0.0f;

  // x loads: thread covers row = lane>>2, dims (lane&3)*16 .. +15
  const int xrow = lane >> 2, xcol = (lane & 3) * 16;
  const float* xb = x + ((size_t)b * T_ + row0 + xrow) * C_ + xcol;

  f32x4 nx0 = *(const f32x4*)xb;
  f32x4 nx1 = *(const f32x4*)(xb + 4);
  f32x4 nx2 = *(const f32x4*)(xb + 8);
  f32x4 nx3 = *(const f32x4*)(xb + 12);

  const int wa0 = (xrow * 128 + xcol * 2) ^ ((xrow & 7) << 4);
  const int wa1 = (xrow * 128 + xcol * 2 + 16) ^ ((xrow & 7) << 4);
  const int ra0 = (l15 * 128 + g * 16) ^ ((l15 & 7) << 4);
  const int ra1 = (l15 * 128 + 64 + g * 16) ^ ((l15 & 7) << 4);

  for (int c64 = 0; c64 < 16; c64++) {
    f32x4 c0 = nx0, c1 = nx1, c2 = nx2, c3 = nx3;
    if (c64 < 15) {
      const float* nsrc = xb + (c64 + 1) * 64;
      nx0 = *(const f32x4*)nsrc;
      nx1 = *(const f32x4*)(nsrc + 4);
      nx2 = *(const f32x4*)(nsrc + 8);
      nx3 = *(const f32x4*)(nsrc + 12);
    }
    u32x4 h0, h1;
    h0[0] = cvtpk(c0[0], c0[1]); h0[1] = cvtpk(c0[2], c0[3]);
    h0[2] = cvtpk(c1[0], c1[1]); h0[3] = cvtpk(c1[2], c1[3]);
    h1[0] = cvtpk(c2[0], c2[1]); h1[1] = cvtpk(c2[2], c2[3]);
    h1[2] = cvtpk(c3[0], c3[1]); h1[3] = cvtpk(c3[2], c3[3]);
    char* xsb = (char*)xs[c64 & 1];
    *(u32x4*)(xsb + wa0) = h0;
    *(u32x4*)(xsb + wa1) = h1;

    bf16x8 xa0 = *(const bf16x8*)(xsb + ra0);   // dims g*8+j
    bf16x8 xa1 = *(const bf16x8*)(xsb + ra1);   // dims 32+g*8+j

    #pragma unroll
    for (int w = 0; w < 3; w++) {
      const ushort* wb = WtF + (((size_t)(w * 16 + c64) * 2) * 4) * 512 + lane * 8;
      #pragma unroll
      for (int nt = 0; nt < 4; nt++) {
        bf16x8 b0 = *(const bf16x8*)(wb + nt * 512);
        bf16x8 b1 = *(const bf16x8*)(wb + 2048 + nt * 512);
        acc[w][nt] = MFMA(xa0, b0, acc[w][nt]);
        acc[w][nt] = MFMA(xa1, b1, acc[w][nt]);
      }
    }
  }

  // epilogue: C-frag col = l15 (n within tile), row = g*4+r (t offset)
  char* kdst = Kb + ((size_t)b * 64 + (row0 >> 6)) * 8192;
  const int G = row0 >> 5;                     // same for all lanes/r
  char* vdst = VaF + ((size_t)b * 128 + G) * 4096;
  #pragma unroll
  for (int nt = 0; nt < 4; nt++) {
    int n = nt * 16 + l15;
    #pragma unroll
    for (int r = 0; r < 4; r++) {
      int t = row0 + g * 4 + r;
      Qg[((size_t)b * T_ + t) * H_ + n] = f2bf(acc[0][nt][r]);
      int key = t & 63;
      *(ushort*)(kdst + ((key * 128 + n * 2) ^ ((key & 7) << 4))) = f2bf(acc[1][nt][r]);
      int k5 = t & 31;
      int gp = ((k5 >> 4) << 1) | ((k5 >> 2) & 1);
      int js = ((k5 >> 3) & 1) * 4 + (k5 & 3);
      *(ushort*)(vdst + nt * 1024 + (gp * 16 + l15) * 16 + js * 2) = f2bf(acc[2][nt][r]);
    }
  }
}

// ---------------------------------------------------------------------------
// Flash attention, swapped QK^T + in-register softmax (cvt_pk + permlane32_swap).
// Block = 4 waves x 16 q-rows. 64-key tiles, dbuf LDS (32KB), 1 barrier/iter.
__global__ __launch_bounds__(256) void attn(const ushort* __restrict__ Qg,
                                            const char* __restrict__ Kb,
                                            const char* __restrict__ VaF,
                                            float* __restrict__ Op,
                                            float* __restrict__ Ds,
                                            float* __restrict__ out,
                                            int KT) {
  __shared__ __align__(16) char kv[2][16384];   // [buf][K 8KB | V 8KB]
  const int tid = threadIdx.x;
  const int lane = tid & 63, wid = tid >> 6;
  const int bid = blockIdx.x;
  const int s = bid >> 8, r8 = bid & 255;
  const int b = r8 >> 6, qt = r8 & 63;
  const int l15 = lane & 15, g = lane >> 4;

  // Q B-frag: lane l15 = q, k = dim g*8+j  (per k-chunk)
  const ushort* qp = Qg + ((size_t)b * T_ + qt * 64 + wid * 16 + l15) * H_ + g * 8;
  bf16x8 qa0 = *(const bf16x8*)qp;
  bf16x8 qa1 = *(const bf16x8*)(qp + 32);

  f32x4 oacc[4];          // C: O[q=l15][dim = 16*ntd + g*4 + r]
  #pragma unroll
  for (int nt = 0; nt < 4; nt++) oacc[nt] = (f32x4)0.0f;
  float dsum = 0.0f;

  const char* kbase = Kb + (size_t)b * 64 * 8192;
  const char* vbase = VaF + (size_t)b * 128 * 4096;
  const int it0 = s * KT;

  auto stage = [&](int buf, int it) {
    char* dst = kv[buf] + tid * 16;
    const char* ks = kbase + (size_t)it * 8192 + tid * 16;
    const char* vs = vbase + (size_t)it * 8192 + tid * 16;
    gload_lds16(ks, dst);
    gload_lds16(ks + 4096, dst + 4096);
    gload_lds16(vs, dst + 8192);
    gload_lds16(vs + 4096, dst + 12288);
  };

  stage(0, it0);
  __syncthreads();

  for (int it = 0; it < KT; it++) {
    const int cur = it & 1;
    if (it + 1 < KT) stage(cur ^ 1, it0 + it + 1);
    const char* kl = kv[cur];
    const char* vl = kv[cur] + 8192;

    // S^T = K Q^T: sacc[nt] C-frag: row = key (nt*16+g*4+r), col = q (l15)
    f32x4 sacc[4];
    #pragma unroll
    for (int nt = 0; nt < 4; nt++) sacc[nt] = (f32x4)0.0f;
    #pragma unroll
    for (int nt = 0; nt < 4; nt++) {
      int kr = nt * 16 + l15;
      bf16x8 ka0 = *(const bf16x8*)(kl + ((kr * 128 + g * 16) ^ ((kr & 7) << 4)));
      bf16x8 ka1 = *(const bf16x8*)(kl + ((kr * 128 + 64 + g * 16) ^ ((kr & 7) << 4)));
      sacc[nt] = MFMA(ka0, qa0, sacc[nt]);
      sacc[nt] = MFMA(ka1, qa1, sacc[nt]);
    }

    // softmax numerators in-register; pack pairs of adjacent keys
    uint t0[4], t1[4];
    #pragma unroll
    for (int nt = 0; nt < 4; nt++) {
      float p0 = __builtin_amdgcn_exp2f(sacc[nt][0] * 0.18033688011112042f);
      float p1 = __builtin_amdgcn_exp2f(sacc[nt][1] * 0.18033688011112042f);
      float p2 = __builtin_amdgcn_exp2f(sacc[nt][2] * 0.18033688011112042f);
      float p3 = __builtin_amdgcn_exp2f(sacc[nt][3] * 0.18033688011112042f);
      dsum += (p0 + p1) + (p2 + p3);
      t0[nt] = cvtpk(p0, p1);
      t1[nt] = cvtpk(p2, p3);
    }

    // build PV B-frags (P^T): 2 permlane32_swap per 32-key chunk
    #pragma unroll
    for (int kk = 0; kk < 2; kk++) {
      uint x0 = t0[2 * kk], y0 = t0[2 * kk + 1];
      uint x1 = t1[2 * kk], y1 = t1[2 * kk + 1];
      asm volatile("v_permlane32_swap_b32 %0, %1" : "+v"(x0), "+v"(y0));
      asm volatile("v_permlane32_swap_b32 %0, %1" : "+v"(x1), "+v"(y1));
      union { uint u[4]; bf16x8 v; } pf;
      pf.u[0] = x0; pf.u[1] = x1; pf.u[2] = y0; pf.u[3] = y1;
      // O^T += V^T P^T : A = V frag (phi-ordered), B = P^T frag
      #pragma unroll
      for (int ntd = 0; ntd < 4; ntd++) {
        bf16x8 va = *(const bf16x8*)(vl + kk * 4096 + ntd * 1024 + lane * 16);
        oacc[ntd] = MFMA(va, pf.v, oacc[ntd]);
      }
    }
    __syncthreads();
  }

  // denominator: reduce over g groups (disjoint key subsets), q = l15
  dsum += __shfl_xor(dsum, 16, 64);
  dsum += __shfl_xor(dsum, 32, 64);

  const int q = qt * 64 + wid * 16 + l15;
  if (Op != nullptr) {
    float* ob = Op + ((size_t)(s * 4 + b) * T_ + q) * H_;
    #pragma unroll
    for (int nt = 0; nt < 4; nt++)
      #pragma unroll
      for (int r = 0; r < 4; r++) ob[nt * 16 + g * 4 + r] = oacc[nt][r];
    if (g == 0) Ds[(size_t)(s * 4 + b) * T_ + q] = dsum;
  } else {
    float inv = 1.0f / dsum;
    float* ob = out + ((size_t)b * T_ + q) * H_;
    #pragma unroll
    for (int nt = 0; nt < 4; nt++)
      #pragma unroll
      for (int r = 0; r < 4; r++) ob[nt * 16 + g * 4 + r] = oacc[nt][r] * inv;
  }
}

// ---------------------------------------------------------------------------
// out[row][h] = sum_s Op[s][row][h] / sum_s Ds[s][row]
__global__ __launch_bounds__(256) void reduce_seg(const float* __restrict__ Op,
                                                  const float* __restrict__ Ds,
                                                  float* __restrict__ out, int seg) {
  int i = blockIdx.x * 256 + threadIdx.x;       // over 4*4096*16 f32x4 groups
  size_t e = (size_t)i * 4;
  int row = (int)(e >> 6);
  f32x4 o = (f32x4)0.0f;
  float d = 0.0f;
  for (int s = 0; s < seg; s++) {
    o += *(const f32x4*)(Op + (size_t)s * (4u * T_ * H_) + e);
    d += Ds[(size_t)s * (4u * T_) + row];
  }
  *(f32x4*)(out + e) = o * (1.0f / d);
}

// ---------------------------------------------------------------------------
extern "C" void kernel_launch(void* const* d_in, const int* in_sizes, int n_in,
                              void* d_out, int out_size, void* d_ws, size_t ws_size,
                              hipStream_t stream) {
  const float* x  = (const float*)d_in[0];
  const float* Wq = (const float*)d_in[1];
  const float* Wk = (const float*)d_in[2];
  const float* Wv = (const float*)d_in[3];
  float* out = (float*)d_out;

  char* ws = (char*)d_ws;
  size_t off = 0;
  auto take = [&](size_t n) -> void* {
    void* p = ws + off;
    off = (off + n + 255) & ~(size_t)255;
    return p;
  };
  ushort* Qg  = (ushort*)take((size_t)B_ * T_ * H_ * 2);   // 2 MB
  char*   Kb  = (char*)take((size_t)B_ * T_ * H_ * 2);     // 2 MB (blocked)
  char*   VaF = (char*)take((size_t)B_ * T_ * H_ * 2);     // 2 MB (frag order)
  ushort* WtF = (ushort*)take((size_t)3 * H_ * C_ * 2);    // 384 KB

  // key-split: largest seg whose partials fit the workspace
  int seg = 1;
  float* Op = nullptr;
  float* Ds = nullptr;
  for (int sg = 4; sg >= 2; sg >>= 1) {
    size_t need = off + (size_t)sg * B_ * T_ * H_ * 4 + 256 + (size_t)sg * B_ * T_ * 4 + 256;
    if (need <= ws_size) {
      seg = sg;
      Op = (float*)take((size_t)sg * B_ * T_ * H_ * 4);
      Ds = (float*)take((size_t)sg * B_ * T_ * 4);
      break;
    }
  }
  int KT = 64 / seg;                                       // 64-key tiles

  wt_prep<<<768, 256, 0, stream>>>(Wq, Wk, Wv, WtF);
  qkv_proj<<<B_ * (T_ / 16), 64, 0, stream>>>(x, WtF, Qg, Kb, VaF);
  attn<<<B_ * (T_ / 64) * seg, 256, 0, stream>>>(Qg, Kb, VaF, Op, Ds, out, KT);
  if (Op) reduce_seg<<<(B_ * T_ * H_ / 4 + 255) / 256, 256, 0, stream>>>(Op, Ds, out, seg);
}

// Round 5
// 61.633 us; speedup vs baseline: 3.3896x; 1.1294x over previous
//
#include <hip/hip_runtime.h>
#include <hip/hip_bf16.h>

#define B_ 4
#define T_ 4096
#define C_ 1024
#define H_ 64

typedef float  f32x4  __attribute__((ext_vector_type(4)));
typedef short  bf16x8 __attribute__((ext_vector_type(8)));
typedef uint   u32x4  __attribute__((ext_vector_type(4)));

static __device__ __forceinline__ ushort f2bf(float f) {
  union { float f; uint u; } v; v.f = f;
  uint u = v.u;
  u += 0x7FFFu + ((u >> 16) & 1u);   // round-to-nearest-even
  return (ushort)(u >> 16);
}

// pack two f32 -> u32 of 2 bf16 (lo = s0, hi = s1), RTNE  [gfx950; no builtin]
static __device__ __forceinline__ uint cvtpk(float s0, float s1) {
  uint r;
  asm("v_cvt_pk_bf16_f32 %0, %1, %2" : "=v"(r) : "v"(s0), "v"(s1));
  return r;
}

static __device__ __forceinline__ void gload_lds16(const void* g, void* l) {
  __builtin_amdgcn_global_load_lds(
      (const __attribute__((address_space(1))) unsigned int*)g,
      (__attribute__((address_space(3))) unsigned int*)l, 16, 0, 0);
}

#define MFMA(a, b, c) __builtin_amdgcn_mfma_f32_16x16x32_bf16(a, b, c, 0, 0, 0)

// ---------------------------------------------------------------------------
// WtF: W in B-frag order: [w][c64 16][kc 2][nt 4][lane 64][j 8]
//   value = W_w[c = c64*64 + kc*32 + (lane>>4)*8 + j][n = nt*16 + (lane&15)]
__global__ __launch_bounds__(256) void wt_prep(const float* __restrict__ Wq,
                                               const float* __restrict__ Wk,
                                               const float* __restrict__ Wv,
                                               ushort* __restrict__ WtF) {
  int idx = blockIdx.x * 256 + threadIdx.x;   // 3*16*2*4*64*8 = 196608
  int j = idx & 7, lane = (idx >> 3) & 63, nt = (idx >> 9) & 3;
  int kc = (idx >> 11) & 1, c64 = (idx >> 12) & 15, w = idx >> 16;
  int l15 = lane & 15, g = lane >> 4;
  int c = c64 * 64 + kc * 32 + g * 8 + j;
  int n = nt * 16 + l15;
  const float* W = (w == 0) ? Wq : (w == 1) ? Wk : Wv;
  WtF[idx] = f2bf(W[c * 64 + n]);
}

// ---------------------------------------------------------------------------
// QKV projection v3: 4-wave blocks (64 rows), x direct-to-A-frag, W via
// global_load_lds into shared dbuf LDS (issue-early so barrier drains are free).
__global__ __launch_bounds__(256) void qkv_proj(const float* __restrict__ x,
                                                const ushort* __restrict__ WtF,
                                                ushort* __restrict__ Qg,
                                                char* __restrict__ Kb,
                                                char* __restrict__ VaF) {
  __shared__ __align__(16) ushort wl[2][12288];   // 2 x 24KB: [w 3][kc 2][nt 4][lane 64][j 8]
  const int tid = threadIdx.x;
  const int lane = tid & 63, wid = tid >> 6;
  const int l15 = lane & 15, g = lane >> 4;
  const int b = blockIdx.x >> 6, rt = blockIdx.x & 63;
  const int wrow = rt * 64 + wid * 16;            // wave's 16 rows

  f32x4 acc[3][4];
  #pragma unroll
  for (int w = 0; w < 3; w++)
    #pragma unroll
    for (int nt = 0; nt < 4; nt++) acc[w][nt] = (f32x4)0.0f;

  // per lane: A-frag row = wrow + l15, k-cols g*8 + [0,8) per 32-chunk
  const float* xr = x + ((size_t)b * T_ + wrow + l15) * C_ + g * 8;

  auto stagew = [&](int buf, int c64) {
    char* dst = (char*)wl[buf] + tid * 16;
    const char* src = (const char*)WtF + (size_t)c64 * 8192 + tid * 16;
    #pragma unroll
    for (int p = 0; p < 6; p++)   // p = w*2 + half(4KB)
      gload_lds16(src + (p >> 1) * 131072 + (p & 1) * 4096, dst + p * 4096);
  };

  f32x4 xp[2][4];
  stagew(0, 0);
  #pragma unroll
  for (int i = 0; i < 2; i++) {
    xp[0][2 * i]     = *(const f32x4*)(xr + i * 32);
    xp[0][2 * i + 1] = *(const f32x4*)(xr + i * 32 + 4);
  }
  __syncthreads();

  #pragma unroll
  for (int t = 0; t < 16; t++) {
    const int cur = t & 1;
    if (t < 15) {                 // issue-early: next W tile + next x chunk
      stagew(cur ^ 1, t + 1);
      const float* nx = xr + (t + 1) * 64;
      #pragma unroll
      for (int i = 0; i < 2; i++) {
        xp[cur ^ 1][2 * i]     = *(const f32x4*)(nx + i * 32);
        xp[cur ^ 1][2 * i + 1] = *(const f32x4*)(nx + i * 32 + 4);
      }
    }
    bf16x8 xa[2];
    #pragma unroll
    for (int kc = 0; kc < 2; kc++) {
      union { uint u[4]; bf16x8 v; } h;
      f32x4 c0 = xp[cur][2 * kc], c1 = xp[cur][2 * kc + 1];
      h.u[0] = cvtpk(c0[0], c0[1]); h.u[1] = cvtpk(c0[2], c0[3]);
      h.u[2] = cvtpk(c1[0], c1[1]); h.u[3] = cvtpk(c1[2], c1[3]);
      xa[kc] = h.v;
    }
    const char* wb = (const char*)wl[cur] + lane * 16;
    __builtin_amdgcn_s_setprio(1);
    #pragma unroll
    for (int w = 0; w < 3; w++)
      #pragma unroll
      for (int kc = 0; kc < 2; kc++)
        #pragma unroll
        for (int nt = 0; nt < 4; nt++) {
          bf16x8 wf = *(const bf16x8*)(wb + w * 8192 + kc * 4096 + nt * 1024);
          acc[w][nt] = MFMA(xa[kc], wf, acc[w][nt]);
        }
    __builtin_amdgcn_s_setprio(0);
    __syncthreads();
  }

  // epilogue: C-frag col = l15 (n), row = g*4 + r (t offset)  [m89-verified]
  char* kdst = Kb + ((size_t)b * 64 + rt) * 8192;
  char* vdst = VaF + ((size_t)b * 128 + (wrow >> 5)) * 4096;
  #pragma unroll
  for (int nt = 0; nt < 4; nt++) {
    int n = nt * 16 + l15;
    #pragma unroll
    for (int r = 0; r < 4; r++) {
      int tt = wrow + g * 4 + r;
      Qg[((size_t)b * T_ + tt) * H_ + n] = f2bf(acc[0][nt][r]);
      int key = tt & 63;
      *(ushort*)(kdst + ((key * 128 + n * 2) ^ ((key & 7) << 4))) = f2bf(acc[1][nt][r]);
      int k5 = tt & 31;
      int gp = ((k5 >> 4) << 1) | ((k5 >> 2) & 1);
      int js = ((k5 >> 3) & 1) * 4 + (k5 & 3);
      *(ushort*)(vdst + nt * 1024 + (gp * 16 + l15) * 16 + js * 2) = f2bf(acc[2][nt][r]);
    }
  }
}

// ---------------------------------------------------------------------------
// Flash attention v3: 32 q-rows/wave (2x16 subtiles) -> K/V frags loaded once,
// reused for both subtiles (halves LDS-read bytes per q-row).
__global__ __launch_bounds__(256) void attn(const ushort* __restrict__ Qg,
                                            const char* __restrict__ Kb,
                                            const char* __restrict__ VaF,
                                            float* __restrict__ Op,
                                            float* __restrict__ Ds,
                                            float* __restrict__ out,
                                            int KT) {
  __shared__ __align__(16) char kv[2][16384];   // [buf][K 8KB | V 8KB]
  const int tid = threadIdx.x;
  const int lane = tid & 63, wid = tid >> 6;
  const int bid = blockIdx.x;
  const int s = bid >> 7, r7 = bid & 127;
  const int b = r7 >> 5, qt = r7 & 31;
  const int l15 = lane & 15, g = lane >> 4;

  // Q B-frags for 2 q-subtiles: lane l15 = q, k = dim g*8+j
  bf16x8 qa[2][2];
  #pragma unroll
  for (int qs = 0; qs < 2; qs++) {
    const ushort* qp = Qg + ((size_t)b * T_ + qt * 128 + wid * 32 + qs * 16 + l15) * H_ + g * 8;
    qa[qs][0] = *(const bf16x8*)qp;
    qa[qs][1] = *(const bf16x8*)(qp + 32);
  }

  f32x4 oacc[2][4];       // C: O[q=l15][dim = 16*ntd + g*4 + r] per subtile
  #pragma unroll
  for (int qs = 0; qs < 2; qs++)
    #pragma unroll
    for (int nt = 0; nt < 4; nt++) oacc[qs][nt] = (f32x4)0.0f;
  float dsum[2] = {0.f, 0.f};

  const char* kbase = Kb + (size_t)b * 64 * 8192;
  const char* vbase = VaF + (size_t)b * 128 * 4096;
  const int it0 = s * KT;

  auto stage = [&](int buf, int it) {
    char* dst = kv[buf] + tid * 16;
    const char* ks = kbase + (size_t)it * 8192 + tid * 16;
    const char* vs = vbase + (size_t)it * 8192 + tid * 16;
    gload_lds16(ks, dst);
    gload_lds16(ks + 4096, dst + 4096);
    gload_lds16(vs, dst + 8192);
    gload_lds16(vs + 4096, dst + 12288);
  };

  stage(0, it0);
  __syncthreads();

  for (int it = 0; it < KT; it++) {
    const int cur = it & 1;
    if (it + 1 < KT) stage(cur ^ 1, it0 + it + 1);
    const char* kl = kv[cur];
    const char* vl = kv[cur] + 8192;

    // S^T = K Q^T for both subtiles; K frags read once
    f32x4 sacc[2][4];
    #pragma unroll
    for (int qs = 0; qs < 2; qs++)
      #pragma unroll
      for (int nt = 0; nt < 4; nt++) sacc[qs][nt] = (f32x4)0.0f;
    __builtin_amdgcn_s_setprio(1);
    #pragma unroll
    for (int nt = 0; nt < 4; nt++) {
      int kr = nt * 16 + l15;
      bf16x8 ka0 = *(const bf16x8*)(kl + ((kr * 128 + g * 16) ^ ((kr & 7) << 4)));
      bf16x8 ka1 = *(const bf16x8*)(kl + ((kr * 128 + 64 + g * 16) ^ ((kr & 7) << 4)));
      #pragma unroll
      for (int qs = 0; qs < 2; qs++) {
        sacc[qs][nt] = MFMA(ka0, qa[qs][0], sacc[qs][nt]);
        sacc[qs][nt] = MFMA(ka1, qa[qs][1], sacc[qs][nt]);
      }
    }
    __builtin_amdgcn_s_setprio(0);

    // softmax numerators in-register
    uint t0[2][4], t1[2][4];
    #pragma unroll
    for (int qs = 0; qs < 2; qs++)
      #pragma unroll
      for (int nt = 0; nt < 4; nt++) {
        float p0 = __builtin_amdgcn_exp2f(sacc[qs][nt][0] * 0.18033688011112042f);
        float p1 = __builtin_amdgcn_exp2f(sacc[qs][nt][1] * 0.18033688011112042f);
        float p2 = __builtin_amdgcn_exp2f(sacc[qs][nt][2] * 0.18033688011112042f);
        float p3 = __builtin_amdgcn_exp2f(sacc[qs][nt][3] * 0.18033688011112042f);
        dsum[qs] += (p0 + p1) + (p2 + p3);
        t0[qs][nt] = cvtpk(p0, p1);
        t1[qs][nt] = cvtpk(p2, p3);
      }

    // build P^T B-frags (permlane32_swap) and accumulate O^T += V^T P^T
    #pragma unroll
    for (int kk = 0; kk < 2; kk++) {
      bf16x8 pf[2];
      #pragma unroll
      for (int qs = 0; qs < 2; qs++) {
        uint x0 = t0[qs][2 * kk], y0 = t0[qs][2 * kk + 1];
        uint x1 = t1[qs][2 * kk], y1 = t1[qs][2 * kk + 1];
        asm volatile("v_permlane32_swap_b32 %0, %1" : "+v"(x0), "+v"(y0));
        asm volatile("v_permlane32_swap_b32 %0, %1" : "+v"(x1), "+v"(y1));
        union { uint u[4]; bf16x8 v; } pfu;
        pfu.u[0] = x0; pfu.u[1] = x1; pfu.u[2] = y0; pfu.u[3] = y1;
        pf[qs] = pfu.v;
      }
      __builtin_amdgcn_s_setprio(1);
      #pragma unroll
      for (int ntd = 0; ntd < 4; ntd++) {
        bf16x8 va = *(const bf16x8*)(vl + kk * 4096 + ntd * 1024 + lane * 16);
        oacc[0][ntd] = MFMA(va, pf[0], oacc[0][ntd]);
        oacc[1][ntd] = MFMA(va, pf[1], oacc[1][ntd]);
      }
      __builtin_amdgcn_s_setprio(0);
    }
    __syncthreads();
  }

  // epilogue per subtile
  #pragma unroll
  for (int qs = 0; qs < 2; qs++) {
    float d = dsum[qs];
    d += __shfl_xor(d, 16, 64);
    d += __shfl_xor(d, 32, 64);
    const int q = qt * 128 + wid * 32 + qs * 16 + l15;
    if (Op != nullptr) {
      float* ob = Op + ((size_t)(s * 4 + b) * T_ + q) * H_;
      #pragma unroll
      for (int nt = 0; nt < 4; nt++)
        #pragma unroll
        for (int r = 0; r < 4; r++) ob[nt * 16 + g * 4 + r] = oacc[qs][nt][r];
      if (g == 0) Ds[(size_t)(s * 4 + b) * T_ + q] = d;
    } else {
      float inv = 1.0f / d;
      float* ob = out + ((size_t)b * T_ + q) * H_;
      #pragma unroll
      for (int nt = 0; nt < 4; nt++)
        #pragma unroll
        for (int r = 0; r < 4; r++) ob[nt * 16 + g * 4 + r] = oacc[qs][nt][r] * inv;
    }
  }
}

// ---------------------------------------------------------------------------
// out[row][h] = sum_s Op[s][row][h] / sum_s Ds[s][row]
__global__ __launch_bounds__(256) void reduce_seg(const float* __restrict__ Op,
                                                  const float* __restrict__ Ds,
                                                  float* __restrict__ out, int seg) {
  int i = blockIdx.x * 256 + threadIdx.x;       // over 4*4096*16 f32x4 groups
  size_t e = (size_t)i * 4;
  int row = (int)(e >> 6);
  f32x4 o = (f32x4)0.0f;
  float d = 0.0f;
  for (int s = 0; s < seg; s++) {
    o += *(const f32x4*)(Op + (size_t)s * (4u * T_ * H_) + e);
    d += Ds[(size_t)s * (4u * T_) + row];
  }
  *(f32x4*)(out + e) = o * (1.0f / d);
}

// ---------------------------------------------------------------------------
extern "C" void kernel_launch(void* const* d_in, const int* in_sizes, int n_in,
                              void* d_out, int out_size, void* d_ws, size_t ws_size,
                              hipStream_t stream) {
  const float* x  = (const float*)d_in[0];
  const float* Wq = (const float*)d_in[1];
  const float* Wk = (const float*)d_in[2];
  const float* Wv = (const float*)d_in[3];
  float* out = (float*)d_out;

  char* ws = (char*)d_ws;
  size_t off = 0;
  auto take = [&](size_t n) -> void* {
    void* p = ws + off;
    off = (off + n + 255) & ~(size_t)255;
    return p;
  };
  ushort* Qg  = (ushort*)take((size_t)B_ * T_ * H_ * 2);   // 2 MB
  char*   Kb  = (char*)take((size_t)B_ * T_ * H_ * 2);     // 2 MB (blocked)
  char*   VaF = (char*)take((size_t)B_ * T_ * H_ * 2);     // 2 MB (frag order)
  ushort* WtF = (ushort*)take((size_t)3 * H_ * C_ * 2);    // 384 KB

  // key-split: largest seg whose partials fit the workspace
  int seg = 1;
  float* Op = nullptr;
  float* Ds = nullptr;
  for (int sg = 4; sg >= 2; sg >>= 1) {
    size_t need = off + (size_t)sg * B_ * T_ * H_ * 4 + 256 + (size_t)sg * B_ * T_ * 4 + 256;
    if (need <= ws_size) {
      seg = sg;
      Op = (float*)take((size_t)sg * B_ * T_ * H_ * 4);
      Ds = (float*)take((size_t)sg * B_ * T_ * 4);
      break;
    }
  }
  int KT = 64 / seg;                                       // 64-key tiles/segment

  wt_prep<<<768, 256, 0, stream>>>(Wq, Wk, Wv, WtF);
  qkv_proj<<<B_ * 64, 256, 0, stream>>>(x, WtF, Qg, Kb, VaF);
  attn<<<B_ * (T_ / 128) * seg, 256, 0, stream>>>(Qg, Kb, VaF, Op, Ds, out, KT);
  if (Op) reduce_seg<<<(B_ * T_ * H_ / 4 + 255) / 256, 256, 0, stream>>>(Op, Ds, out, seg);
}

// Round 6
// 54.881 us; speedup vs baseline: 3.8066x; 1.1230x over previous
//
#include <hip/hip_runtime.h>
#include <hip/hip_bf16.h>

#define B_ 4
#define T_ 4096
#define C_ 1024
#define H_ 64

typedef float  f32x4  __attribute__((ext_vector_type(4)));
typedef short  bf16x8 __attribute__((ext_vector_type(8)));
typedef uint   u32x4  __attribute__((ext_vector_type(4)));

static __device__ __forceinline__ ushort f2bf(float f) {
  union { float f; uint u; } v; v.f = f;
  uint u = v.u;
  u += 0x7FFFu + ((u >> 16) & 1u);   // round-to-nearest-even
  return (ushort)(u >> 16);
}

// pack two f32 -> u32 of 2 bf16 (lo = s0, hi = s1), RTNE  [gfx950; no builtin]
static __device__ __forceinline__ uint cvtpk(float s0, float s1) {
  uint r;
  asm("v_cvt_pk_bf16_f32 %0, %1, %2" : "=v"(r) : "v"(s0), "v"(s1));
  return r;
}

static __device__ __forceinline__ void gload_lds16(const void* g, void* l) {
  __builtin_amdgcn_global_load_lds(
      (const __attribute__((address_space(1))) unsigned int*)g,
      (__attribute__((address_space(3))) unsigned int*)l, 16, 0, 0);
}

#define MFMA(a, b, c) __builtin_amdgcn_mfma_f32_16x16x32_bf16(a, b, c, 0, 0, 0)

// ---------------------------------------------------------------------------
// WtF: W in B-frag order: [w][c64 16][kc 2][nt 4][lane 64][j 8]
//   value = W_w[c = c64*64 + kc*32 + (lane>>4)*8 + j][n = nt*16 + (lane&15)]
__global__ __launch_bounds__(256) void wt_prep(const float* __restrict__ Wq,
                                               const float* __restrict__ Wk,
                                               const float* __restrict__ Wv,
                                               ushort* __restrict__ WtF) {
  int idx = blockIdx.x * 256 + threadIdx.x;   // 3*16*2*4*64*8 = 196608
  int j = idx & 7, lane = (idx >> 3) & 63, nt = (idx >> 9) & 3;
  int kc = (idx >> 11) & 1, c64 = (idx >> 12) & 15, w = idx >> 16;
  int l15 = lane & 15, g = lane >> 4;
  int c = c64 * 64 + kc * 32 + g * 8 + j;
  int n = nt * 16 + l15;
  const float* W = (w == 0) ? Wq : (w == 1) ? Wk : Wv;
  WtF[idx] = f2bf(W[c * 64 + n]);
}

// ---------------------------------------------------------------------------
// QKV projection v4: 4-wave blocks (64 rows), x direct-to-A-frag 2-deep
// prefetch, W via global_load_lds dbuf, COUNTED-vmcnt raw barriers (T4).
// Outputs:
//   Qg:  [b][t][h] bf16 linear
//   KaF: per-(b, t/64) 8KB A-frag tile [kc 2][nt 4][lane 64][j 8]:
//        elem = K[key = nt*16+(lane&15)][dim = kc*32+(lane>>4)*8+j], key=t&63
//   VaF: per-(b, t/32) 4KB frag-block [ntd 4][lane 64][j 8] (phi-permuted keys)
__global__ __launch_bounds__(256) void qkv_proj(const float* __restrict__ x,
                                                const ushort* __restrict__ WtF,
                                                ushort* __restrict__ Qg,
                                                char* __restrict__ KaF,
                                                char* __restrict__ VaF) {
  __shared__ __align__(16) ushort wl[2][12288];   // 2 x 24KB W frags
  const int tid = threadIdx.x;
  const int lane = tid & 63, wid = tid >> 6;
  const int l15 = lane & 15, g = lane >> 4;
  const int b = blockIdx.x >> 6, rt = blockIdx.x & 63;
  const int wrow = rt * 64 + wid * 16;            // wave's 16 rows

  f32x4 acc[3][4];
  #pragma unroll
  for (int w = 0; w < 3; w++)
    #pragma unroll
    for (int nt = 0; nt < 4; nt++) acc[w][nt] = (f32x4)0.0f;

  // A-frag row = wrow + l15, k-cols g*8 + [0,8) per 32-chunk
  const float* xr = x + ((size_t)b * T_ + wrow + l15) * C_ + g * 8;

  auto stagew = [&](int buf, int c64) {
    char* dst = (char*)wl[buf] + tid * 16;
    const char* src = (const char*)WtF + (size_t)c64 * 8192 + tid * 16;
    #pragma unroll
    for (int p = 0; p < 6; p++)   // p = w*2 + half(4KB)
      gload_lds16(src + (p >> 1) * 131072 + (p & 1) * 4096, dst + p * 4096);
  };

  f32x4 xp[3][4];                 // 2-deep x prefetch ring (static idx: full unroll)
  auto xload = [&](int slot, int t) {
    const float* src = xr + t * 64;
    xp[slot][0] = *(const f32x4*)src;
    xp[slot][1] = *(const f32x4*)(src + 4);
    xp[slot][2] = *(const f32x4*)(src + 32);
    xp[slot][3] = *(const f32x4*)(src + 36);
  };

  stagew(0, 0);
  xload(0, 0);
  xload(1, 1);
  asm volatile("s_waitcnt vmcnt(8)" ::: "memory");   // stagew(0) landed; x in flight
  __builtin_amdgcn_s_barrier();
  __builtin_amdgcn_sched_barrier(0);

  #pragma unroll
  for (int t = 0; t < 16; t++) {
    const int cur = t & 1;
    if (t < 15) stagew(cur ^ 1, t + 1);
    if (t < 14) xload((t + 2) % 3, t + 2);

    const int slot = t % 3;
    bf16x8 xa[2];
    #pragma unroll
    for (int kc = 0; kc < 2; kc++) {
      union { uint u[4]; bf16x8 v; } h;
      f32x4 c0 = xp[slot][2 * kc], c1 = xp[slot][2 * kc + 1];
      h.u[0] = cvtpk(c0[0], c0[1]); h.u[1] = cvtpk(c0[2], c0[3]);
      h.u[2] = cvtpk(c1[0], c1[1]); h.u[3] = cvtpk(c1[2], c1[3]);
      xa[kc] = h.v;
    }
    const char* wb = (const char*)wl[cur] + lane * 16;
    __builtin_amdgcn_s_setprio(1);
    #pragma unroll
    for (int w = 0; w < 3; w++)
      #pragma unroll
      for (int kc = 0; kc < 2; kc++)
        #pragma unroll
        for (int nt = 0; nt < 4; nt++) {
          bf16x8 wf = *(const bf16x8*)(wb + w * 8192 + kc * 4096 + nt * 1024);
          acc[w][nt] = MFMA(xa[kc], wf, acc[w][nt]);
        }
    __builtin_amdgcn_s_setprio(0);

    if (t < 15) {
      // counted drain: complete stagew(t+1) (+older x), keep x(t+2) in flight
      if (t < 14) asm volatile("s_waitcnt vmcnt(4)" ::: "memory");
      else        asm volatile("s_waitcnt vmcnt(0)" ::: "memory");
      __builtin_amdgcn_s_barrier();
      __builtin_amdgcn_sched_barrier(0);
    }
  }

  // epilogue: C-frag col = l15 (n), row = g*4 + r (t offset)  [m89-verified]
  char* kdst = KaF + ((size_t)b * 64 + rt) * 8192;
  char* vdst = VaF + ((size_t)b * 128 + (wrow >> 5)) * 4096;
  #pragma unroll
  for (int nt = 0; nt < 4; nt++) {
    int n = nt * 16 + l15;
    int kc = n >> 5, gp2 = (n >> 3) & 3, j2 = n & 7;
    #pragma unroll
    for (int r = 0; r < 4; r++) {
      int tt = wrow + g * 4 + r;
      Qg[((size_t)b * T_ + tt) * H_ + n] = f2bf(acc[0][nt][r]);
      int key = tt & 63;
      *(ushort*)(kdst + kc * 4096 + (key >> 4) * 1024 +
                 (gp2 * 16 + (key & 15)) * 16 + j2 * 2) = f2bf(acc[1][nt][r]);
      int k5 = tt & 31;
      int gp = ((k5 >> 4) << 1) | ((k5 >> 2) & 1);
      int js = ((k5 >> 3) & 1) * 4 + (k5 & 3);
      *(ushort*)(vdst + nt * 1024 + (gp * 16 + l15) * 16 + js * 2) = f2bf(acc[2][nt][r]);
    }
  }
}

// ---------------------------------------------------------------------------
// Flash attention v4: NO LDS, NO barriers. K/V MFMA fragments read directly
// from global in frag order (perfectly coalesced, L2-resident). K ping-pong
// prefetched one tile ahead. 32 q-rows/wave (2 subtiles), key-split partials.
__global__ __launch_bounds__(256, 2) void attn(const ushort* __restrict__ Qg,
                                               const char* __restrict__ KaF,
                                               const char* __restrict__ VaF,
                                               float* __restrict__ Op,
                                               float* __restrict__ Ds,
                                               float* __restrict__ out,
                                               int KT) {
  const int tid = threadIdx.x;
  const int lane = tid & 63, wid = tid >> 6;
  const int bid = blockIdx.x;
  const int b = bid & 3;                 // b = bid&3: each XCD serves one batch
  const int r2 = bid >> 2;
  const int qt = r2 & 31, s = r2 >> 5;
  const int l15 = lane & 15, g = lane >> 4;

  // Q B-frags for 2 q-subtiles: lane l15 = q, k = dim g*8+j
  bf16x8 qa[2][2];
  #pragma unroll
  for (int qs = 0; qs < 2; qs++) {
    const ushort* qp = Qg + ((size_t)b * T_ + qt * 128 + wid * 32 + qs * 16 + l15) * H_ + g * 8;
    qa[qs][0] = *(const bf16x8*)qp;
    qa[qs][1] = *(const bf16x8*)(qp + 32);
  }

  f32x4 oacc[2][4];       // C: O[q=l15][dim = 16*ntd + g*4 + r] per subtile
  #pragma unroll
  for (int qs = 0; qs < 2; qs++)
    #pragma unroll
    for (int nt = 0; nt < 4; nt++) oacc[qs][nt] = (f32x4)0.0f;
  float dsum[2] = {0.f, 0.f};

  const char* kbase = KaF + (size_t)b * 64 * 8192;
  const char* vbase = VaF + (size_t)b * 128 * 4096;
  const int it0 = s * KT;

  bf16x8 kaA[8], kaB[8];  // ping-pong K frags: [kc*4 + nt]
  {
    const char* kt = kbase + (size_t)it0 * 8192 + lane * 16;
    #pragma unroll
    for (int i = 0; i < 8; i++) kaA[i] = *(const bf16x8*)(kt + i * 1024);
  }

  auto body = [&](int it, bf16x8 (&kaC)[8], bf16x8 (&kaN)[8]) {
    // issue V frag loads early (consumed after QK^T + softmax)
    const char* vt = vbase + (size_t)(it0 + it) * 8192 + lane * 16;
    bf16x8 va[8];
    #pragma unroll
    for (int i = 0; i < 8; i++) va[i] = *(const bf16x8*)(vt + i * 1024);

    // S^T = K Q^T (both subtiles share K frags)
    f32x4 sacc[2][4];
    #pragma unroll
    for (int qs = 0; qs < 2; qs++)
      #pragma unroll
      for (int nt = 0; nt < 4; nt++) sacc[qs][nt] = (f32x4)0.0f;
    __builtin_amdgcn_s_setprio(1);
    #pragma unroll
    for (int nt = 0; nt < 4; nt++)
      #pragma unroll
      for (int qs = 0; qs < 2; qs++) {
        sacc[qs][nt] = MFMA(kaC[nt], qa[qs][0], sacc[qs][nt]);
        sacc[qs][nt] = MFMA(kaC[4 + nt], qa[qs][1], sacc[qs][nt]);
      }
    __builtin_amdgcn_s_setprio(0);

    // prefetch next K tile
    if (it + 1 < KT) {
      const char* kt = kbase + (size_t)(it0 + it + 1) * 8192 + lane * 16;
      #pragma unroll
      for (int i = 0; i < 8; i++) kaN[i] = *(const bf16x8*)(kt + i * 1024);
    }

    // softmax numerators in-register
    uint t0[2][4], t1[2][4];
    #pragma unroll
    for (int qs = 0; qs < 2; qs++)
      #pragma unroll
      for (int nt = 0; nt < 4; nt++) {
        float p0 = __builtin_amdgcn_exp2f(sacc[qs][nt][0] * 0.18033688011112042f);
        float p1 = __builtin_amdgcn_exp2f(sacc[qs][nt][1] * 0.18033688011112042f);
        float p2 = __builtin_amdgcn_exp2f(sacc[qs][nt][2] * 0.18033688011112042f);
        float p3 = __builtin_amdgcn_exp2f(sacc[qs][nt][3] * 0.18033688011112042f);
        dsum[qs] += (p0 + p1) + (p2 + p3);
        t0[qs][nt] = cvtpk(p0, p1);
        t1[qs][nt] = cvtpk(p2, p3);
      }

    // build P^T B-frags (permlane32_swap) and accumulate O^T += V^T P^T
    #pragma unroll
    for (int kk = 0; kk < 2; kk++) {
      bf16x8 pf[2];
      #pragma unroll
      for (int qs = 0; qs < 2; qs++) {
        uint x0 = t0[qs][2 * kk], y0 = t0[qs][2 * kk + 1];
        uint x1 = t1[qs][2 * kk], y1 = t1[qs][2 * kk + 1];
        asm volatile("v_permlane32_swap_b32 %0, %1" : "+v"(x0), "+v"(y0));
        asm volatile("v_permlane32_swap_b32 %0, %1" : "+v"(x1), "+v"(y1));
        union { uint u[4]; bf16x8 v; } pfu;
        pfu.u[0] = x0; pfu.u[1] = x1; pfu.u[2] = y0; pfu.u[3] = y1;
        pf[qs] = pfu.v;
      }
      __builtin_amdgcn_s_setprio(1);
      #pragma unroll
      for (int ntd = 0; ntd < 4; ntd++) {
        oacc[0][ntd] = MFMA(va[kk * 4 + ntd], pf[0], oacc[0][ntd]);
        oacc[1][ntd] = MFMA(va[kk * 4 + ntd], pf[1], oacc[1][ntd]);
      }
      __builtin_amdgcn_s_setprio(0);
    }
  };

  for (int it = 0; it < KT; it += 2) {   // KT is even (16/32/64)
    body(it, kaA, kaB);
    body(it + 1, kaB, kaA);
  }

  // epilogue per subtile
  #pragma unroll
  for (int qs = 0; qs < 2; qs++) {
    float d = dsum[qs];
    d += __shfl_xor(d, 16, 64);
    d += __shfl_xor(d, 32, 64);
    const int q = qt * 128 + wid * 32 + qs * 16 + l15;
    if (Op != nullptr) {
      float* ob = Op + ((size_t)(s * 4 + b) * T_ + q) * H_;
      #pragma unroll
      for (int nt = 0; nt < 4; nt++)
        #pragma unroll
        for (int r = 0; r < 4; r++) ob[nt * 16 + g * 4 + r] = oacc[qs][nt][r];
      if (g == 0) Ds[(size_t)(s * 4 + b) * T_ + q] = d;
    } else {
      float inv = 1.0f / d;
      float* ob = out + ((size_t)b * T_ + q) * H_;
      #pragma unroll
      for (int nt = 0; nt < 4; nt++)
        #pragma unroll
        for (int r = 0; r < 4; r++) ob[nt * 16 + g * 4 + r] = oacc[qs][nt][r] * inv;
    }
  }
}

// ---------------------------------------------------------------------------
// out[row][h] = sum_s Op[s][row][h] / sum_s Ds[s][row]
__global__ __launch_bounds__(256) void reduce_seg(const float* __restrict__ Op,
                                                  const float* __restrict__ Ds,
                                                  float* __restrict__ out, int seg) {
  int i = blockIdx.x * 256 + threadIdx.x;       // over 4*4096*16 f32x4 groups
  size_t e = (size_t)i * 4;
  int row = (int)(e >> 6);
  f32x4 o = (f32x4)0.0f;
  float d = 0.0f;
  for (int s = 0; s < seg; s++) {
    o += *(const f32x4*)(Op + (size_t)s * (4u * T_ * H_) + e);
    d += Ds[(size_t)s * (4u * T_) + row];
  }
  *(f32x4*)(out + e) = o * (1.0f / d);
}

// ---------------------------------------------------------------------------
extern "C" void kernel_launch(void* const* d_in, const int* in_sizes, int n_in,
                              void* d_out, int out_size, void* d_ws, size_t ws_size,
                              hipStream_t stream) {
  const float* x  = (const float*)d_in[0];
  const float* Wq = (const float*)d_in[1];
  const float* Wk = (const float*)d_in[2];
  const float* Wv = (const float*)d_in[3];
  float* out = (float*)d_out;

  char* ws = (char*)d_ws;
  size_t off = 0;
  auto take = [&](size_t n) -> void* {
    void* p = ws + off;
    off = (off + n + 255) & ~(size_t)255;
    return p;
  };
  ushort* Qg  = (ushort*)take((size_t)B_ * T_ * H_ * 2);   // 2 MB
  char*   KaF = (char*)take((size_t)B_ * T_ * H_ * 2);     // 2 MB (frag order)
  char*   VaF = (char*)take((size_t)B_ * T_ * H_ * 2);     // 2 MB (frag order)
  ushort* WtF = (ushort*)take((size_t)3 * H_ * C_ * 2);    // 384 KB

  // key-split: largest seg whose partials fit the workspace
  int seg = 1;
  float* Op = nullptr;
  float* Ds = nullptr;
  for (int sg = 4; sg >= 2; sg >>= 1) {
    size_t need = off + (size_t)sg * B_ * T_ * H_ * 4 + 256 + (size_t)sg * B_ * T_ * 4 + 256;
    if (need <= ws_size) {
      seg = sg;
      Op = (float*)take((size_t)sg * B_ * T_ * H_ * 4);
      Ds = (float*)take((size_t)sg * B_ * T_ * 4);
      break;
    }
  }
  int KT = 64 / seg;                                       // 64-key tiles/segment

  wt_prep<<<768, 256, 0, stream>>>(Wq, Wk, Wv, WtF);
  qkv_proj<<<B_ * 64, 256, 0, stream>>>(x, WtF, Qg, KaF, VaF);
  attn<<<B_ * (T_ / 128) * seg, 256, 0, stream>>>(Qg, KaF, VaF, Op, Ds, out, KT);
  if (Op) reduce_seg<<<(B_ * T_ * H_ / 4 + 255) / 256, 256, 0, stream>>>(Op, Ds, out, seg);
}